// Round 3
// baseline (37.776 us; speedup 1.0000x reference)
//
#include <hip/hip_runtime.h>
#include <math.h>

#define GHM_DELTA 0.1f
#define GHM_EPS   1e-12f

__device__ __forceinline__ float softplus_ref(float x) {
    // jax.nn.softplus(x) == max(x,0) + log1p(exp(-|x|))
    return fmaxf(x, 0.0f) + log1pf(expf(-fabsf(x)));
}

__device__ __forceinline__ float sigmoid_ref(float x) {
    return 1.0f / (1.0f + expf(-x));
}

// Fused kernel: 512 blocks x 512 threads. Block bx owns i-tile [bx*32, bx*32+32).
// Thread layout: ilane = tid&31 (which i), jpart = tid>>5 (which 1024-j slice).
// Each block stages the FULL g vector (64KB LDS) from logits/targets inline,
// counts pairs, reduces the 16 j-partials per i in LDS, computes the loss for
// its 32 i's, and writes one double partial pair. No atomics anywhere.
__global__ __launch_bounds__(512) void ghm_fused(
    const float* __restrict__ logits,
    const int*   __restrict__ targets,
    const float* __restrict__ pos_weight,
    double*      __restrict__ partials,   // [gridDim.x * 2]
    int n)                                 // 16384
{
    __shared__ float gj[16384];           // 64 KB
    __shared__ int   pc[16][32];          // j-partial counts per i

    const int tid = threadIdx.x;
    const int bx  = blockIdx.x;

    // Stage g[j] = |sigmoid(x_j) - y_j| for ALL j (512 thr x 8 iters x float4).
    {
        const float4* l4 = reinterpret_cast<const float4*>(logits);
        const int4*   t4 = reinterpret_cast<const int4*>(targets);
        float4*       g4 = reinterpret_cast<float4*>(gj);
        const int nf4 = n >> 2;           // 4096
        for (int k = tid; k < nf4; k += 512) {
            float4 x = l4[k];
            int4   y = t4[k];
            float4 r;
            r.x = fabsf(sigmoid_ref(x.x) - (float)y.x);
            r.y = fabsf(sigmoid_ref(x.y) - (float)y.y);
            r.z = fabsf(sigmoid_ref(x.z) - (float)y.z);
            r.w = fabsf(sigmoid_ref(x.w) - (float)y.w);
            g4[k] = r;
        }
    }
    __syncthreads();

    const int ilane = tid & 31;
    const int jpart = tid >> 5;           // 0..15
    const int ig    = bx * 32 + ilane;
    const float gi  = gj[ig];

    // 1024 compares per thread; 4 independent chains for ILP.
    // LDS read addr: 2 distinct addresses per wave (jpart pairs) -> free 2-way.
    int c0 = 0, c1 = 0, c2 = 0, c3 = 0;
    const float4* lj = reinterpret_cast<const float4*>(gj) + jpart * 256;
    #pragma unroll 8
    for (int jj = 0; jj < 256; ++jj) {
        float4 v = lj[jj];
        c0 += (fabsf(gi - v.x) <= GHM_DELTA) ? 1 : 0;
        c1 += (fabsf(gi - v.y) <= GHM_DELTA) ? 1 : 0;
        c2 += (fabsf(gi - v.z) <= GHM_DELTA) ? 1 : 0;
        c3 += (fabsf(gi - v.w) <= GHM_DELTA) ? 1 : 0;
    }
    pc[jpart][ilane] = (c0 + c1) + (c2 + c3);
    __syncthreads();

    // Wave 0 finishes: full counts -> loss terms -> 64-lane shfl reduce.
    if (tid < 64) {
        double wd = 0.0, pd = 0.0;
        if (tid < 32) {
            int cnt = 0;
            #pragma unroll
            for (int p = 0; p < 16; ++p) cnt += pc[p][tid];
            const int i = bx * 32 + tid;
            float x  = logits[i];
            float y  = (float)targets[i];
            float GD   = (float)cnt / GHM_DELTA;
            float beta = (float)n / (GD + GHM_EPS);
            float pw   = pos_weight[0];
            float per  = pw * y * softplus_ref(-x) + (1.0f - y) * softplus_ref(x);
            wd = (double)(beta * per);
            pd = (double)per;
        }
        #pragma unroll
        for (int off = 32; off >= 1; off >>= 1) {
            wd += __shfl_down(wd, off, 64);
            pd += __shfl_down(pd, off, 64);
        }
        if (tid == 0) {
            partials[bx * 2]     = wd;
            partials[bx * 2 + 1] = pd;
        }
    }
}

// Single-block deterministic final reduce of nb partial pairs.
__global__ __launch_bounds__(512) void ghm_reduce(
    const double* __restrict__ partials,
    float* __restrict__ out,
    int nb, int n)
{
    __shared__ double red[16];
    const int t = threadIdx.x;
    double wd = 0.0, pd = 0.0;
    for (int k = t; k < nb; k += 512) {
        wd += partials[2 * k];
        pd += partials[2 * k + 1];
    }
    #pragma unroll
    for (int off = 32; off >= 1; off >>= 1) {
        wd += __shfl_down(wd, off, 64);
        pd += __shfl_down(pd, off, 64);
    }
    const int wave = t >> 6;
    if ((t & 63) == 0) { red[wave * 2] = wd; red[wave * 2 + 1] = pd; }
    __syncthreads();
    if (t == 0) {
        double sw = 0.0, sp = 0.0;
        for (int k = 0; k < 8; ++k) { sw += red[2 * k]; sp += red[2 * k + 1]; }
        out[0] = (float)(sw / (double)n);
        out[1] = (float)(sp / (double)n);
    }
}

extern "C" void kernel_launch(void* const* d_in, const int* in_sizes, int n_in,
                              void* d_out, int out_size, void* d_ws, size_t ws_size,
                              hipStream_t stream) {
    const float* logits     = (const float*)d_in[0];
    const int*   targets    = (const int*)d_in[1];
    const float* pos_weight = (const float*)d_in[2];
    float* out = (float*)d_out;
    const int n = in_sizes[0];            // 16384

    const int nb = n / 32;                // 512 blocks
    double* partials = (double*)d_ws;     // nb*2 doubles

    ghm_fused<<<nb, 512, 0, stream>>>(logits, targets, pos_weight, partials, n);
    ghm_reduce<<<1, 512, 0, stream>>>(partials, out, nb, n);
}

// Round 4
// 33.233 us; speedup vs baseline: 1.1367x; 1.1367x over previous
//
#include <hip/hip_runtime.h>
#include <math.h>

#define GHM_DELTA 0.1f
#define GHM_EPS   1e-12f
#define N_FIX     16384
#define TI        512          // i's per block
#define TJ        512          // j's per block (LDS chunk)
#define MI        8            // i's per thread (register-blocked)
#define TH_I      (TI / MI)    // 64 threads along i
#define TH_J      4            // j-split groups (= waves per block)
#define NBI       (N_FIX / TI) // 32
#define NBJ       (N_FIX / TJ) // 32

__device__ __forceinline__ float softplus_ref(float x) {
    return fmaxf(x, 0.0f) + log1pf(expf(-fabsf(x)));
}
__device__ __forceinline__ float sigmoid_ref(float x) {
    return 1.0f / (1.0f + expf(-x));
}

// K1: pair-count. Grid (NBI, NBJ) x 256 threads. Thread layout: il = tid&63
// (which 8-i group), jp = tid>>6 (= wave id, which 128-j slice). Each thread
// holds 8 gi in registers and streams its j-slice from LDS via float4 with
// wave-uniform addresses (broadcast, conflict-free). Partial counts written
// once to pcount[by][i] -- no atomics, no init required.
__global__ __launch_bounds__(256) void ghm_pair(
    const float* __restrict__ logits,
    const int*   __restrict__ targets,
    int*         __restrict__ pcount)    // [NBJ][N_FIX]
{
    __shared__ float gj[TJ];             // 2 KB
    __shared__ int   pc[TH_J][MI][TH_I]; // 8 KB, [jp][m][il] conflict-free

    const int tid = threadIdx.x;
    const int bx  = blockIdx.x;          // i-tile
    const int by  = blockIdx.y;          // j-chunk
    const int il  = tid & 63;
    const int jp  = tid >> 6;            // == wave id

    // Stage j-chunk g values (2 per thread).
    const int jbase = by * TJ;
    for (int k = tid; k < TJ; k += 256) {
        float x = logits[jbase + k];
        float y = (float)targets[jbase + k];
        gj[k] = fabsf(sigmoid_ref(x) - y);
    }

    // Compute this thread's 8 gi in registers.
    const int i0 = bx * TI + il * MI;
    float gi[MI];
    {
        const float4* lx = reinterpret_cast<const float4*>(logits + i0);
        const int4*   ty = reinterpret_cast<const int4*>(targets + i0);
        float4 x0 = lx[0], x1 = lx[1];
        int4   y0 = ty[0], y1 = ty[1];
        gi[0] = fabsf(sigmoid_ref(x0.x) - (float)y0.x);
        gi[1] = fabsf(sigmoid_ref(x0.y) - (float)y0.y);
        gi[2] = fabsf(sigmoid_ref(x0.z) - (float)y0.z);
        gi[3] = fabsf(sigmoid_ref(x0.w) - (float)y0.w);
        gi[4] = fabsf(sigmoid_ref(x1.x) - (float)y1.x);
        gi[5] = fabsf(sigmoid_ref(x1.y) - (float)y1.y);
        gi[6] = fabsf(sigmoid_ref(x1.z) - (float)y1.z);
        gi[7] = fabsf(sigmoid_ref(x1.w) - (float)y1.w);
    }
    __syncthreads();

    // 128 j's per thread = 32 float4; each float4 reused for 8 i's.
    int c[MI];
    #pragma unroll
    for (int m = 0; m < MI; ++m) c[m] = 0;

    const float4* lj = reinterpret_cast<const float4*>(gj) + jp * (TJ / TH_J / 4);
    #pragma unroll 4
    for (int jj = 0; jj < TJ / TH_J / 4; ++jj) {
        float4 v = lj[jj];               // wave-uniform -> LDS broadcast
        #pragma unroll
        for (int m = 0; m < MI; ++m) {
            c[m] += (fabsf(gi[m] - v.x) <= GHM_DELTA);
            c[m] += (fabsf(gi[m] - v.y) <= GHM_DELTA);
            c[m] += (fabsf(gi[m] - v.z) <= GHM_DELTA);
            c[m] += (fabsf(gi[m] - v.w) <= GHM_DELTA);
        }
    }
    #pragma unroll
    for (int m = 0; m < MI; ++m) pc[jp][m][il] = c[m];
    __syncthreads();

    // 256 threads -> 2 i's each: sum the 4 jp-partials, write int2.
    {
        const int i_loc0 = tid * 2;
        int s[2];
        #pragma unroll
        for (int q = 0; q < 2; ++q) {
            const int i_loc = i_loc0 + q;
            const int mm = i_loc & (MI - 1);
            const int ll = i_loc >> 3;
            s[q] = pc[0][mm][ll] + pc[1][mm][ll] + pc[2][mm][ll] + pc[3][mm][ll];
        }
        int2* dst = reinterpret_cast<int2*>(pcount + (size_t)by * N_FIX + bx * TI);
        dst[tid] = make_int2(s[0], s[1]);
    }
}

// K2: finalize. 32 blocks x 512 threads, i = bx*512 + tid. Sum 32 chunk
// partials, compute loss terms, deterministic block reduce -> bpart[bx][2].
__global__ __launch_bounds__(512) void ghm_finalize(
    const float* __restrict__ logits,
    const int*   __restrict__ targets,
    const float* __restrict__ pos_weight,
    const int*   __restrict__ pcount,
    double*      __restrict__ bpart)
{
    __shared__ double red[16];
    const int tid = threadIdx.x;
    const int i = blockIdx.x * 512 + tid;

    int cnt = 0;
    #pragma unroll
    for (int by = 0; by < NBJ; ++by) cnt += pcount[(size_t)by * N_FIX + i];

    float x  = logits[i];
    float y  = (float)targets[i];
    float GD   = (float)cnt / GHM_DELTA;
    float beta = (float)N_FIX / (GD + GHM_EPS);
    float pw   = pos_weight[0];
    float per  = pw * y * softplus_ref(-x) + (1.0f - y) * softplus_ref(x);
    double wd = (double)(beta * per);
    double pd = (double)per;

    #pragma unroll
    for (int off = 32; off >= 1; off >>= 1) {
        wd += __shfl_down(wd, off, 64);
        pd += __shfl_down(pd, off, 64);
    }
    const int wave = tid >> 6;
    if ((tid & 63) == 0) { red[wave * 2] = wd; red[wave * 2 + 1] = pd; }
    __syncthreads();
    if (tid == 0) {
        double sw = 0.0, sp = 0.0;
        #pragma unroll
        for (int k = 0; k < 8; ++k) { sw += red[2 * k]; sp += red[2 * k + 1]; }
        bpart[blockIdx.x * 2]     = sw;
        bpart[blockIdx.x * 2 + 1] = sp;
    }
}

// K3: final reduce of 32 block partials (single wave, fixed order).
__global__ __launch_bounds__(64) void ghm_reduce(
    const double* __restrict__ bpart, float* __restrict__ out, int nb, int n)
{
    double sw = 0.0, sp = 0.0;
    for (int k = threadIdx.x; k < nb; k += 64) {
        sw += bpart[2 * k];
        sp += bpart[2 * k + 1];
    }
    #pragma unroll
    for (int off = 32; off >= 1; off >>= 1) {
        sw += __shfl_down(sw, off, 64);
        sp += __shfl_down(sp, off, 64);
    }
    if (threadIdx.x == 0) {
        out[0] = (float)(sw / (double)n);
        out[1] = (float)(sp / (double)n);
    }
}

extern "C" void kernel_launch(void* const* d_in, const int* in_sizes, int n_in,
                              void* d_out, int out_size, void* d_ws, size_t ws_size,
                              hipStream_t stream) {
    const float* logits     = (const float*)d_in[0];
    const int*   targets    = (const int*)d_in[1];
    const float* pos_weight = (const float*)d_in[2];
    float* out = (float*)d_out;
    const int n = in_sizes[0];           // 16384

    // ws: pcount[NBJ][N] ints (2 MB) | bpart[32*2] doubles
    int*    pcount = (int*)d_ws;
    double* bpart  = (double*)((char*)d_ws + (size_t)NBJ * N_FIX * sizeof(int));

    dim3 grid1(NBI, NBJ);
    ghm_pair<<<grid1, 256, 0, stream>>>(logits, targets, pcount);
    ghm_finalize<<<NBI, 512, 0, stream>>>(logits, targets, pos_weight,
                                          pcount, bpart);
    ghm_reduce<<<1, 64, 0, stream>>>(bpart, out, NBI, n);
}